// Round 2
// baseline (419.412 us; speedup 1.0000x reference)
//
#include <hip/hip_runtime.h>
#include <hip/hip_fp16.h>

constexpr int NN   = 131072;   // total nodes
constexpr int PP   = 4096;     // nodes per graph
constexpr int BG   = 32;       // graphs
constexpr int EE   = 2097152;  // edges
constexpr int IND  = 64;
constexpr int HH   = 128;
constexpr int CAP  = 81920;    // per-graph slot capacity (65536 mean + pad4 + slack)
constexpr float EPSV   = 1e-5f;
constexpr float SLOPEV = 0.01f;

typedef _Float16 h16x8 __attribute__((ext_vector_type(8)));
typedef float f32x4  __attribute__((ext_vector_type(4)));
typedef unsigned u32x4 __attribute__((ext_vector_type(4)));

__device__ __forceinline__ __half2 bits2h(unsigned u) { __half2 h; *(unsigned*)&h = u; return h; }
__device__ __forceinline__ unsigned h2bits(__half2 h) { return *(unsigned*)&h; }

// ---------------- W -> MFMA B-fragment prepack (f16, device body) ----------------
template <int K>
__device__ __forceinline__ void packw_body(const float* __restrict__ W,
                                           unsigned short* __restrict__ pw, int t) {
    if (t >= K * 16) return;
    int lane = t & 63, nt = (t >> 6) & 7, kt = t >> 9;
    int kbase = kt * 32 + ((lane >> 4) & 3) * 8;
    int col   = nt * 16 + (lane & 15);
    for (int j = 0; j < 8; j++)
        pw[t * 8 + j] = __half_as_ushort(__float2half_rn(W[(kbase + j) * HH + col]));
}

// ---------------- fused prep: feature->f16 cvt + init + weight prepack + csr2 zero ----------------
__global__ __launch_bounds__(256) void k_prep(const float* __restrict__ features,
                                              unsigned* __restrict__ f16x,
                                              const float* __restrict__ W1,
                                              unsigned short* __restrict__ pw1,
                                              const float* __restrict__ W2,
                                              unsigned short* __restrict__ pw2,
                                              int* __restrict__ gcur,
                                              float* __restrict__ racc,
                                              unsigned* __restrict__ csr2) {
    int b = blockIdx.x, t = threadIdx.x;
    if (b < 8192) {                     // f16 convert: NN*IND = 8192*256 float4s
        int i = b * 256 + t;
        float4 v = ((const float4*)features)[i];
        __half2 lo = __floats2half2_rn(v.x, v.y);
        __half2 hi = __floats2half2_rn(v.z, v.w);
        ((uint2*)f16x)[i] = make_uint2(h2bits(lo), h2bits(hi));
        return;
    }
    if (b == 8192) {                    // init cursors + readout accumulators
        if (t < BG) gcur[t * 16] = t * CAP;
        for (int i = t; i < 2 * BG * HH; i += 256) racc[i] = 0.f;
        return;
    }
    if (b < 8197) { packw_body<64>(W1, pw1, (b - 8193) * 256 + t); return; }
    if (b < 8205) { packw_body<128>(W2, pw2, (b - 8197) * 256 + t); return; }
    // zero csr2 pad region: BG*CAP words = 163840 uint4 = 2560 blocks
    ((uint4*)csr2)[(b - 8205) * 256 + t] = make_uint4(0, 0, 0, 0);
}

// ---------------- pass 1: 32-way partition of edges by graph ----------------
__global__ __launch_bounds__(256) void k_part(const int* __restrict__ src,
                                              const int* __restrict__ dst,
                                              const float* __restrict__ ew,
                                              int* __restrict__ gcur,
                                              uint2* __restrict__ recs) {
    __shared__ int cnt[32];
    __shared__ int start[32];
    __shared__ int gbase[32];
    __shared__ uint2 stage[4096];
    int t = threadIdx.x;
    int ebase = blockIdx.x * 4096;
    if (t < 32) cnt[t] = 0;
    __syncthreads();
    int es[16]; int ed[16]; float ev[16];
#pragma unroll
    for (int k = 0; k < 16; k++) {
        int e = ebase + k * 256 + t;
        es[k] = src[e]; ed[k] = dst[e]; ev[k] = ew[e];
        atomicAdd(&cnt[es[k] >> 12], 1);
    }
    __syncthreads();
    if (t == 0) {
        int run = 0;
        for (int g = 0; g < 32; g++) { start[g] = run; run += cnt[g]; }
    }
    __syncthreads();
    if (t < 32) {
        gbase[t] = atomicAdd(&gcur[t * 16], cnt[t]);
        cnt[t] = start[t];                      // becomes cursor
    }
    __syncthreads();
#pragma unroll
    for (int k = 0; k < 16; k++) {
        int g = es[k] >> 12;
        int pos = atomicAdd(&cnt[g], 1);
        stage[pos] = make_uint2((unsigned)(es[k] & 4095) | ((unsigned)(ed[k] & 4095) << 12) |
                                ((unsigned)g << 24), __float_as_uint(ev[k]));
    }
    __syncthreads();
    for (int i = t; i < 4096; i += 256) {
        uint2 r = stage[i];
        int g = r.x >> 24;
        recs[gbase[g] + (i - start[g])] = r;
    }
}

// ---------------- build phase A: per-(graph,chunk) histograms ----------------
__global__ __launch_bounds__(1024) void k_hist(const uint2* __restrict__ recs,
                                               const int* __restrict__ gcur,
                                               int* __restrict__ shist,
                                               int* __restrict__ dhist) {
    __shared__ int hs[4096];
    __shared__ int hd[4096];
    int t = threadIdx.x;
    int g = blockIdx.x >> 3, c = blockIdx.x & 7;
    int n = gcur[g * 16] - g * CAP;
    int lo = (n * c) >> 3, hi = (n * (c + 1)) >> 3;
    ((int4*)hs)[t] = make_int4(0, 0, 0, 0);
    ((int4*)hd)[t] = make_int4(0, 0, 0, 0);
    __syncthreads();
    const uint2* base = recs + (size_t)g * CAP;
    for (int i = lo + t; i < hi; i += 1024) {
        unsigned x = base[i].x;
        atomicAdd(&hs[x & 4095], 1);
        atomicAdd(&hd[(x >> 12) & 4095], 1);
    }
    __syncthreads();
    ((int4*)(shist + (size_t)blockIdx.x * 4096))[t] = ((int4*)hs)[t];
    ((int4*)(dhist + (size_t)blockIdx.x * 4096))[t] = ((int4*)hd)[t];
}

// ---------------- build phase B: degrees, rsqrt, padded offsets, chunk cursor bases ----------------
__global__ __launch_bounds__(1024) void k_offs(int* __restrict__ shist,
                                               int* __restrict__ dhist,
                                               float* __restrict__ rs_s,
                                               float* __restrict__ rsd,
                                               int* __restrict__ degd,
                                               int* __restrict__ offs) {
    __shared__ int partial[1024];
    int t = threadIdx.x, g = blockIdx.x;
    int sdeg[4] = {0, 0, 0, 0}, ddeg[4] = {0, 0, 0, 0};
#pragma unroll
    for (int c = 0; c < 8; c++) {
        int4 sv = ((const int4*)(shist + (size_t)(g * 8 + c) * 4096))[t];
        int4 dv = ((const int4*)(dhist + (size_t)(g * 8 + c) * 4096))[t];
        sdeg[0] += sv.x; sdeg[1] += sv.y; sdeg[2] += sv.z; sdeg[3] += sv.w;
        ddeg[0] += dv.x; ddeg[1] += dv.y; ddeg[2] += dv.z; ddeg[3] += dv.w;
    }
    int pdeg[4];
#pragma unroll
    for (int j = 0; j < 4; j++) {
        int idx = t * 4 + j;
        int vs = sdeg[j]; if (vs < 1) vs = 1;
        rs_s[g * PP + idx] = rsqrtf((float)vs);
        int vd = ddeg[j]; if (vd < 1) vd = 1;
        rsd[g * PP + idx]  = rsqrtf((float)vd);
        pdeg[j] = (ddeg[j] + 3) & ~3;           // padded to multiple of 4
        degd[g * PP + idx] = pdeg[j];           // agg loops run over padded count
    }
    partial[t] = pdeg[0] + pdeg[1] + pdeg[2] + pdeg[3];
    __syncthreads();
    for (int off = 1; off < 1024; off <<= 1) {
        int v = partial[t];
        int add = (t >= off) ? partial[t - off] : 0;
        __syncthreads();
        partial[t] = v + add;
        __syncthreads();
    }
    int run = (t == 0) ? 0 : partial[t - 1];
#pragma unroll
    for (int j = 0; j < 4; j++) {
        int idx = t * 4 + j;
        offs[g * PP + idx] = g * CAP + run;
        int nb = run;                           // true edges placed at segment start
        for (int c = 0; c < 8; c++) {
            size_t hidx = (size_t)(g * 8 + c) * 4096 + idx;
            int v = dhist[hidx];
            dhist[hidx] = nb;                   // per-chunk cursor base (graph-relative)
            nb += v;
        }
        run += pdeg[j];                         // pad region stays zero
    }
}

// ---------------- build phase C: counting-sort placement ----------------
__global__ __launch_bounds__(1024) void k_place(const uint2* __restrict__ recs,
                                                const int* __restrict__ gcur,
                                                const int* __restrict__ dhist,
                                                const float* __restrict__ rs_s,
                                                unsigned* __restrict__ csr2) {
    __shared__ int cur[4096];
    __shared__ float rss[4096];
    int t = threadIdx.x;
    int g = blockIdx.x >> 3, c = blockIdx.x & 7;
    int n = gcur[g * 16] - g * CAP;
    int lo = (n * c) >> 3, hi = (n * (c + 1)) >> 3;
    ((int4*)cur)[t] = ((const int4*)(dhist + (size_t)blockIdx.x * 4096))[t];
    ((float4*)rss)[t] = ((const float4*)(rs_s + (size_t)g * PP))[t];
    __syncthreads();
    const uint2* base = recs + (size_t)g * CAP;
    unsigned* cbase = csr2 + (size_t)g * CAP;
    for (int i = lo + t; i < hi; i += 1024) {
        uint2 r = base[i];
        int sl = r.x & 4095, dl = (r.x >> 12) & 4095;
        int pos = atomicAdd(&cur[dl], 1);
        float wf = __uint_as_float(r.y) * rss[sl];
        cbase[pos] = (unsigned)sl | ((unsigned)__half_as_ushort(__float2half(wf)) << 16);
    }
}

// ---------------- f16 edge accumulation primitives ----------------
// edge word: sl(12b) | half-weight<<16 ; broadcast weight bits with v_perm, 2x pk_fma_f16
__device__ __forceinline__ void edge_acc(unsigned rec, uint2 q, __half2& P01, __half2& P23) {
    unsigned wb = __builtin_amdgcn_perm(rec, rec, 0x03020302u);   // {hi16, hi16}
    __half2 w2 = bits2h(wb);
    P01 = __hfma2(w2, bits2h(q.x), P01);
    P23 = __hfma2(w2, bits2h(q.y), P23);
}

template <int ROWW>
__device__ __forceinline__ void gath(const uint2* __restrict__ gb, unsigned loff, u32x4 r,
                                     uint2& d0, uint2& d1, uint2& d2, uint2& d3) {
    d0 = gb[(r[0] & 4095u) * ROWW + loff];
    d1 = gb[(r[1] & 4095u) * ROWW + loff];
    d2 = gb[(r[2] & 4095u) * ROWW + loff];
    d3 = gb[(r[3] & 4095u) * ROWW + loff];
}

__device__ __forceinline__ void macc(u32x4 r, uint2 q0, uint2 q1, uint2 q2, uint2 q3,
                                     __half2& P01, __half2& P23) {
    edge_acc(r[0], q0, P01, P23); edge_acc(r[1], q1, P01, P23);
    edge_acc(r[2], q2, P01, P23); edge_acc(r[3], q3, P01, P23);
}

// ---------------- dual-node f16 aggregation, 2-deep ping-pong gather pipeline ----------------
// csr2 reads are nontemporal (streamed once); gather-table reads stay cached (deg~16 reuse).
// Pipeline may issue one wasted gather/csr2 quad past a segment end: csr2 has a zeroed slack
// region and row indices are masked, so those loads are safe and discarded.
template <int ROWW>   // feature row width in uint2 units (16 for 64-feat, 32 for 128-feat)
__device__ __forceinline__ void agg_dual(const uint2* __restrict__ gb, unsigned loff,
                                         const u32x4* __restrict__ cs4,
                                         int oa, int ca, int ob, int cb,
                                         __half2& A01, __half2& A23,
                                         __half2& B01, __half2& B23) {
    A01 = __float2half2_rn(0.f); A23 = A01; B01 = A01; B23 = A01;
    unsigned a4 = ((unsigned)oa) >> 2, b4 = ((unsigned)ob) >> 2;
    int c0 = ca < cb ? ca : cb;
    int cm = ca < cb ? cb : ca;
    int nq = c0 >> 2;
    if (nq > 0) {
        u32x4 ra0 = __builtin_nontemporal_load(cs4 + a4);
        u32x4 rb0 = __builtin_nontemporal_load(cs4 + b4);
        u32x4 ra1 = __builtin_nontemporal_load(cs4 + a4 + 1);
        u32x4 rb1 = __builtin_nontemporal_load(cs4 + b4 + 1);
        uint2 A0, A1, A2, A3, B0, B1, B2, B3;
        uint2 C0, C1, C2, C3, D0, D1, D2, D3;
        gath<ROWW>(gb, loff, ra0, A0, A1, A2, A3);
        gath<ROWW>(gb, loff, rb0, B0, B1, B2, B3);
        int k = 0;
        for (; k + 2 <= nq; k += 2) {
            gath<ROWW>(gb, loff, ra1, C0, C1, C2, C3);       // issue quad k+1 gathers
            gath<ROWW>(gb, loff, rb1, D0, D1, D2, D3);
            u32x4 ra2 = __builtin_nontemporal_load(cs4 + a4 + k + 2);
            u32x4 rb2 = __builtin_nontemporal_load(cs4 + b4 + k + 2);
            macc(ra0, A0, A1, A2, A3, A01, A23);             // math on quad k
            macc(rb0, B0, B1, B2, B3, B01, B23);
            gath<ROWW>(gb, loff, ra2, A0, A1, A2, A3);       // issue quad k+2 gathers
            gath<ROWW>(gb, loff, rb2, B0, B1, B2, B3);
            u32x4 ra3 = __builtin_nontemporal_load(cs4 + a4 + k + 3);
            u32x4 rb3 = __builtin_nontemporal_load(cs4 + b4 + k + 3);
            macc(ra1, C0, C1, C2, C3, A01, A23);             // math on quad k+1
            macc(rb1, D0, D1, D2, D3, B01, B23);
            ra0 = ra2; rb0 = rb2; ra1 = ra3; rb1 = rb3;
        }
        if (k < nq) {                                         // odd leftover quad
            macc(ra0, A0, A1, A2, A3, A01, A23);
            macc(rb0, B0, B1, B2, B3, B01, B23);
        }
    }
    if (cm > c0) {                               // remainder: one node has extra quads
        bool an = ca > cb;
        unsigned t4 = an ? a4 : b4;
        int kq1 = cm >> 2;
        __half2 E01 = __float2half2_rn(0.f), E23 = E01;
        int nq0 = c0 >> 2;
        u32x4 rr = __builtin_nontemporal_load(cs4 + t4 + nq0);
        for (int k = nq0; k < kq1; k++) {
            uint2 q0, q1, q2, q3;
            gath<ROWW>(gb, loff, rr, q0, q1, q2, q3);
            u32x4 nr = __builtin_nontemporal_load(cs4 + t4 + k + 1);
            macc(rr, q0, q1, q2, q3, E01, E23);
            rr = nr;
        }
        if (an) { A01 = __hadd2(A01, E01); A23 = __hadd2(A23, E23); }
        else    { B01 = __hadd2(B01, E01); B23 = __hadd2(B23, E23); }
    }
}

// ================= FUSED layer 1: f16 gather (quarter-wave/node, dual-node) -> LDS -> f16 MFMA =================
__global__ __launch_bounds__(256) void k_aggemm1(const unsigned* __restrict__ fx,   // [NN*32] f16 words
                                                 const unsigned* __restrict__ csr2,
                                                 const int* __restrict__ offs,
                                                 const int* __restrict__ degd,
                                                 const float* __restrict__ rsd,
                                                 const unsigned short* __restrict__ PW,
                                                 unsigned short* __restrict__ C,
                                                 float* __restrict__ part) {
    constexpr int WP = 36;                       // padded row stride (words); 144 B, 16B-aligned
    __shared__ __align__(16) unsigned lds[64 * WP];
    __shared__ float s1[HH], s2[HH];
    int t = threadIdx.x;
    if (t < HH) { s1[t] = 0.f; s2[t] = 0.f; }
    int bid = blockIdx.x;                        // 2048 blocks
    int xcd = bid & 7, idx = bid >> 3;
    int g = xcd * 4 + (idx >> 6);                // XCD x owns graphs 4x..4x+3
    int node0 = g * PP + (idx & 63) * 64;
    int lane = t & 63, wv = t >> 6;
    int q = lane >> 4, ql = lane & 15;           // quarter-wave: 16 lanes x dwordx2 = 64 feats
    const uint2* gb = (const uint2*)fx + (size_t)((unsigned)(g * PP)) * 16;   // wave-uniform base
    const u32x4* cs4 = (const u32x4*)csr2;
#pragma unroll
    for (int p = 0; p < 2; p++) {                // per pass: quarter handles nodes va, va+1
        int lrA = wv * 16 + p * 8 + q * 2;
        int va = node0 + lrA;
        int2 oo = *(const int2*)(offs + va);
        int2 dd = *(const int2*)(degd + va);
        __half2 A01, A23, B01, B23;
        agg_dual<16>(gb, (unsigned)ql, cs4, oo.x, dd.x, oo.y, dd.y, A01, A23, B01, B23);
        float2 rr2 = *(const float2*)(rsd + va);
        __half2 ha = __float2half2_rn(rr2.x), hb = __float2half2_rn(rr2.y);
        __half2 a0 = __hmul2(A01, ha), a1 = __hmul2(A23, ha);
        __half2 b0 = __hmul2(B01, hb), b1 = __hmul2(B23, hb);
        *(uint2*)&lds[lrA * WP + ql * 2]       = make_uint2(h2bits(a0), h2bits(a1));
        *(uint2*)&lds[(lrA + 1) * WP + ql * 2] = make_uint2(h2bits(b0), h2bits(b1));
    }
    __syncthreads();
    // MFMA: wave wv -> local rows wv*16..+15, K=64, f16
    int m = lane & 15, quad = lane >> 4;
    h16x8 a[2];
#pragma unroll
    for (int kt = 0; kt < 2; kt++)
        a[kt] = *(const h16x8*)&lds[(wv * 16 + m) * WP + kt * 16 + quad * 4];
#pragma unroll
    for (int nt = 0; nt < 8; nt++) {
        f32x4 acc = {0.f, 0.f, 0.f, 0.f};
#pragma unroll
        for (int kt = 0; kt < 2; kt++) {
            h16x8 b = *(const h16x8*)(PW + ((size_t)(kt * 8 + nt) * 64 + lane) * 8);
            acc = __builtin_amdgcn_mfma_f32_16x16x32_f16(a[kt], b, acc, 0, 0, 0);
        }
        int col = nt * 16 + m;
        int r0 = node0 + wv * 16 + quad * 4;
        float ps = 0.f, pq = 0.f;
#pragma unroll
        for (int r = 0; r < 4; r++) {
            __builtin_nontemporal_store(
                (unsigned short)__half_as_ushort(__float2half_rn(acc[r])),
                &C[(size_t)(r0 + r) * HH + col]);
            ps += acc[r]; pq += acc[r] * acc[r];
        }
        atomicAdd(&s1[col], ps);
        atomicAdd(&s2[col], pq);
    }
    __syncthreads();
    if (t < HH) {
        __builtin_nontemporal_store(s1[t], &part[bid * 256 + t]);
        __builtin_nontemporal_store(s2[t], &part[bid * 256 + HH + t]);
    }
}

// ================= FUSED layer 2: f16 gather (half-wave/node, dual-node) -> LDS -> f16 MFMA =================
__global__ __launch_bounds__(256) void k_aggemm2(const unsigned* __restrict__ hsrc,  // [NN*64] f16 words
                                                 const unsigned* __restrict__ csr2,
                                                 const int* __restrict__ offs,
                                                 const int* __restrict__ degd,
                                                 const float* __restrict__ rsd,
                                                 const unsigned short* __restrict__ PW,
                                                 unsigned short* __restrict__ C,
                                                 float* __restrict__ part) {
    constexpr int WP = 68;                       // padded row stride (words); 68%4==0
    __shared__ __align__(16) unsigned lds[64 * WP];
    __shared__ float s1[HH], s2[HH];
    int t = threadIdx.x;
    if (t < HH) { s1[t] = 0.f; s2[t] = 0.f; }
    int bid = blockIdx.x;                        // 2048 blocks
    int xcd = bid & 7, idx = bid >> 3;
    int g = xcd * 4 + (idx >> 6);
    int node0 = g * PP + (idx & 63) * 64;
    int lane = t & 63, wv = t >> 6;
    int half = lane >> 5, sl = lane & 31;        // half-wave: 32 lanes x dwordx2 = 128 feats
    const uint2* gb = (const uint2*)hsrc + (size_t)((unsigned)(g * PP)) * 32;
    const u32x4* cs4 = (const u32x4*)csr2;
#pragma unroll
    for (int p = 0; p < 4; p++) {                // per pass: half-wave handles nodes va, va+1
        int lrA = wv * 16 + p * 4 + half * 2;
        int va = node0 + lrA;
        int2 oo = *(const int2*)(offs + va);
        int2 dd = *(const int2*)(degd + va);
        __half2 A01, A23, B01, B23;
        agg_dual<32>(gb, (unsigned)sl, cs4, oo.x, dd.x, oo.y, dd.y, A01, A23, B01, B23);
        float2 rr2 = *(const float2*)(rsd + va);
        __half2 ha = __float2half2_rn(rr2.x), hb = __float2half2_rn(rr2.y);
        __half2 a0 = __hmul2(A01, ha), a1 = __hmul2(A23, ha);
        __half2 b0 = __hmul2(B01, hb), b1 = __hmul2(B23, hb);
        *(uint2*)&lds[lrA * WP + sl * 2]       = make_uint2(h2bits(a0), h2bits(a1));
        *(uint2*)&lds[(lrA + 1) * WP + sl * 2] = make_uint2(h2bits(b0), h2bits(b1));
    }
    __syncthreads();
    // MFMA: wave wv -> local rows wv*16..+15, K=128, f16
    int m = lane & 15, quad = lane >> 4;
    h16x8 a[4];
#pragma unroll
    for (int kt = 0; kt < 4; kt++)
        a[kt] = *(const h16x8*)&lds[(wv * 16 + m) * WP + kt * 16 + quad * 4];
#pragma unroll
    for (int nt = 0; nt < 8; nt++) {
        f32x4 acc = {0.f, 0.f, 0.f, 0.f};
#pragma unroll
        for (int kt = 0; kt < 4; kt++) {
            h16x8 b = *(const h16x8*)(PW + ((size_t)(kt * 8 + nt) * 64 + lane) * 8);
            acc = __builtin_amdgcn_mfma_f32_16x16x32_f16(a[kt], b, acc, 0, 0, 0);
        }
        int col = nt * 16 + m;
        int r0 = node0 + wv * 16 + quad * 4;
        float ps = 0.f, pq = 0.f;
#pragma unroll
        for (int r = 0; r < 4; r++) {
            __builtin_nontemporal_store(
                (unsigned short)__half_as_ushort(__float2half_rn(acc[r])),
                &C[(size_t)(r0 + r) * HH + col]);
            ps += acc[r]; pq += acc[r] * acc[r];
        }
        atomicAdd(&s1[col], ps);
        atomicAdd(&s2[col], pq);
    }
    __syncthreads();
    if (t < HH) {
        __builtin_nontemporal_store(s1[t], &part[bid * 256 + t]);
        __builtin_nontemporal_store(s2[t], &part[bid * 256 + HH + t]);
    }
}

// ---------------- stage-1 reduction of gemm partials ----------------
__global__ __launch_bounds__(256) void k_red(const float* __restrict__ part,
                                             float* __restrict__ pb) {
    int t = threadIdx.x, b = blockIdx.x;        // 64 blocks
    float s = 0.f;
    for (int r = 0; r < 32; r++) s += part[(size_t)(b * 32 + r) * 256 + t];
    pb[b * 256 + t] = s;
}

// ---------------- reduce + norm coefficients ----------------
__global__ void k_coef(const float* __restrict__ pb, const float* __restrict__ gamma,
                       const float* __restrict__ beta, const float* __restrict__ alpha,
                       float* __restrict__ ab) {
    int t = threadIdx.x;                         // 256 threads
    float s = 0.f;
    for (int b = 0; b < 64; b++) s += pb[b * 256 + t];
    __shared__ float sh[256];
    sh[t] = s;
    __syncthreads();
    if (t < 128) {
        float mu = sh[t] * (1.f / NN);
        float e2 = sh[128 + t] * (1.f / NN);
        float al = alpha[t];
        float var = e2 - (2.f * al - al * al) * mu * mu;
        float a = rsqrtf(var + EPSV) * gamma[t];
        ab[t] = a;
        ab[HH + t] = beta[t] - al * mu * a;
    }
}

// ---------------- fused norm + leaky-relu (+f16 h1 emit) + per-graph readout ----------------
template <bool WRITE>
__global__ __launch_bounds__(256) void k_normro(const unsigned* __restrict__ h,  // f16 pairs
                                                const float* __restrict__ ab,
                                                float* __restrict__ racc,
                                                unsigned* __restrict__ f16o) {
    int fp = threadIdx.x & 63;                   // feature pair
    int q  = threadIdx.x >> 6;                   // 0..3
    int node0 = blockIdx.x * 64;                 // one graph per block
    int g = node0 / PP;
    float a0 = ab[2 * fp], a1 = ab[2 * fp + 1];
    float b0 = ab[HH + 2 * fp], b1 = ab[HH + 2 * fp + 1];
    float s0 = 0.f, s1 = 0.f;
    for (int i = q; i < 64; i += 4) {
        size_t idx = (size_t)(node0 + i) * 64 + fp;
        unsigned v = __builtin_nontemporal_load(&h[idx]);
        __half2 hv = bits2h(v);
        float x0 = fmaf(a0, __low2float(hv),  b0); x0 = x0 > 0.f ? x0 : SLOPEV * x0;
        float x1 = fmaf(a1, __high2float(hv), b1); x1 = x1 > 0.f ? x1 : SLOPEV * x1;
        if (WRITE) {
            __half2 o = __floats2half2_rn(x0, x1);
            __builtin_nontemporal_store(h2bits(o), &f16o[idx]);
        }
        s0 += x0; s1 += x1;
    }
    __shared__ float sh[512];
    sh[threadIdx.x] = s0;
    sh[256 + threadIdx.x] = s1;
    __syncthreads();
    if (q == 0) {
        float t0 = s0 + sh[64 + fp] + sh[128 + fp] + sh[192 + fp];
        float t1 = s1 + sh[256 + 64 + fp] + sh[256 + 128 + fp] + sh[256 + 192 + fp];
        atomicAdd(&racc[g * HH + 2 * fp],     t0);
        atomicAdd(&racc[g * HH + 2 * fp + 1], t1);
    }
}

// ---------------- final head ----------------
__global__ void k_final(const float* __restrict__ racc1, const float* __restrict__ racc2,
                        const float* __restrict__ Wc, float* __restrict__ out) {
    int t = threadIdx.x;                         // 512 = 32*16
    int b = t >> 4, o = t & 15;
    float acc = 0.f;
    for (int f = 0; f < HH; f++) acc += racc1[b * HH + f] * Wc[o * (2 * HH) + f];
    for (int f = 0; f < HH; f++) acc += racc2[b * HH + f] * Wc[o * (2 * HH) + HH + f];
    out[t] = acc * (1.f / PP);
}

extern "C" void kernel_launch(void* const* d_in, const int* in_sizes, int n_in,
                              void* d_out, int out_size, void* d_ws, size_t ws_size,
                              hipStream_t stream) {
    const float* features = (const float*)d_in[0];
    const float* ew       = (const float*)d_in[1];
    const int*   src      = (const int*)d_in[2];
    const int*   dst      = (const int*)d_in[3];
    const float* W1       = (const float*)d_in[4];
    const float* W2       = (const float*)d_in[5];
    const float* Wc       = (const float*)d_in[6];
    const float* gamma1   = (const float*)d_in[7];
    const float* beta1    = (const float*)d_in[8];
    const float* alpha1   = (const float*)d_in[9];
    const float* gamma2   = (const float*)d_in[10];
    const float* beta2    = (const float*)d_in[11];
    const float* alpha2   = (const float*)d_in[12];
    float* out = (float*)d_out;

    char* w = (char*)d_ws;
    // misc block [0, 1 MB)
    int*    gcur   = (int*)(w + 0);                         // 32 * 16 ints
    float*  racc1  = (float*)(w + (16u << 10));             // 16 KB
    float*  racc2  = (float*)(w + (32u << 10));             // contiguous with racc1
    float*  ab1    = (float*)(w + (48u << 10));
    float*  ab2    = (float*)(w + (52u << 10));
    unsigned short* pw1 = (unsigned short*)(w + (64u << 10));   // 16 KB
    unsigned short* pw2 = (unsigned short*)(w + (80u << 10));   // 32 KB
    float*  pb     = (float*)(w + (128u << 10));            // 64 KB
    // arrays
    float*  rs_s   = (float*)(w + (1024u << 10));           // 512 KB
    float*  rsd    = (float*)(w + (1536u << 10));           // 512 KB
    int*    degd   = (int*)(w + (2048u << 10));             // 512 KB
    int*    offs   = (int*)(w + (2560u << 10));             // 512 KB
    float*  part   = (float*)(w + (3u << 20));              // 2 MB: 3..5
    int*    shist  = (int*)(w + (5u << 20));                // 4 MB: 5..9
    int*    dhist  = (int*)(w + (9u << 20));                // 4 MB: 9..13
    unsigned* csr2 = (unsigned*)(w + (13u << 20));          // 10 MB: 13..23
    unsigned* mbuf = (unsigned*)(w + (23u << 20));          // 32 MB: 23..55 (f16 h1-post)
    unsigned* hbuf = (unsigned*)(w + (55u << 20));          // 32 MB: 55..87 (C1 then C2, f16)
    uint2*    recs = (uint2*)(w + (87u << 20));             // 20 MB: 87..107
    unsigned* f16x = (unsigned*)(w + (107u << 20));         // 16 MB: 107..123 (features f16)

    // prep (feature->f16 + init + packw + csr2 zero, fused)
    k_prep<<<10765, 256, 0, stream>>>(features, f16x, W1, pw1, W2, pw2, gcur, racc1, csr2);

    // CSR build
    k_part<<<EE / 4096, 256, 0, stream>>>(src, dst, ew, gcur, recs);
    k_hist<<<BG * 8, 1024, 0, stream>>>(recs, gcur, shist, dhist);
    k_offs<<<BG, 1024, 0, stream>>>(shist, dhist, rs_s, rsd, degd, offs);
    k_place<<<BG * 8, 1024, 0, stream>>>(recs, gcur, dhist, rs_s, csr2);

    // ---- layer 1 (fused agg+gemm; gathers f16 features) ----
    k_aggemm1<<<NN / 64, 256, 0, stream>>>(f16x, csr2, offs, degd, rsd,
                                           pw1, (unsigned short*)hbuf, part);
    k_red<<<64, 256, 0, stream>>>(part, pb);
    k_coef<<<1, 256, 0, stream>>>(pb, gamma1, beta1, alpha1, ab1);
    k_normro<true><<<NN / 64, 256, 0, stream>>>(hbuf, ab1, racc1, mbuf);

    // ---- layer 2 (fused agg+gemm; gathers f16 h1 from mbuf, writes C2 to hbuf) ----
    k_aggemm2<<<NN / 64, 256, 0, stream>>>(mbuf, csr2, offs, degd, rsd,
                                           pw2, (unsigned short*)hbuf, part);
    k_red<<<64, 256, 0, stream>>>(part, pb);
    k_coef<<<1, 256, 0, stream>>>(pb, gamma2, beta2, alpha2, ab2);
    k_normro<false><<<NN / 64, 256, 0, stream>>>(hbuf, ab2, racc2, nullptr);

    // ---- head ----
    k_final<<<1, 512, 0, stream>>>(racc1, racc2, Wc, out);
}

// Round 3
// 370.686 us; speedup vs baseline: 1.1314x; 1.1314x over previous
//
#include <hip/hip_runtime.h>
#include <hip/hip_fp16.h>

constexpr int NN   = 131072;   // total nodes
constexpr int PP   = 4096;     // nodes per graph
constexpr int BG   = 32;       // graphs
constexpr int EE   = 2097152;  // edges
constexpr int IND  = 64;
constexpr int HH   = 128;
constexpr int CAP  = 81920;    // per-graph slot capacity (65536 mean + pad4 + slack)
constexpr float EPSV   = 1e-5f;
constexpr float SLOPEV = 0.01f;

typedef short bf16x8 __attribute__((ext_vector_type(8)));
typedef float f32x4  __attribute__((ext_vector_type(4)));
typedef float f32x2  __attribute__((ext_vector_type(2)));
typedef unsigned u32x4 __attribute__((ext_vector_type(4)));

__device__ __forceinline__ unsigned f2bf(float f) {
    unsigned u = __float_as_uint(f);
    return (u + 0x7FFFu + ((u >> 16) & 1u)) >> 16;      // RNE
}
__device__ __forceinline__ unsigned pack2bf(float lo, float hi) {
    return f2bf(lo) | (f2bf(hi) << 16);
}
__device__ __forceinline__ float bflo(unsigned p) { return __uint_as_float(p << 16); }
__device__ __forceinline__ float bfhi(unsigned p) { return __uint_as_float(p & 0xFFFF0000u); }
__device__ __forceinline__ float w16(unsigned r) {
    return __half2float(__ushort_as_half((unsigned short)(r >> 16)));
}

// ---------------- W -> MFMA B-fragment prepack (device body) ----------------
template <int K>
__device__ __forceinline__ void packw_body(const float* __restrict__ W,
                                           unsigned short* __restrict__ pw, int t) {
    if (t >= K * 16) return;
    int lane = t & 63, nt = (t >> 6) & 7, kt = t >> 9;
    int kbase = kt * 32 + ((lane >> 4) & 3) * 8;
    int col   = nt * 16 + (lane & 15);
    for (int j = 0; j < 8; j++)
        pw[t * 8 + j] = (unsigned short)f2bf(W[(kbase + j) * HH + col]);
}

// ---------------- fused prep: feature->fp8 cvt + init + weight prepack + csr2 zero ----------------
__global__ __launch_bounds__(256) void k_prep(const float* __restrict__ features,
                                              unsigned* __restrict__ f8x,
                                              const float* __restrict__ W1,
                                              unsigned short* __restrict__ pw1,
                                              const float* __restrict__ W2,
                                              unsigned short* __restrict__ pw2,
                                              int* __restrict__ gcur,
                                              float* __restrict__ racc,
                                              unsigned* __restrict__ csr2) {
    int b = blockIdx.x, t = threadIdx.x;
    if (b < 8192) {                     // fp8 convert: NN*16 = 8192*256 words
        int i = b * 256 + t;
        float4 v = ((const float4*)features)[i];
        int w0 = __builtin_amdgcn_cvt_pk_fp8_f32(v.x, v.y, 0, false);
        int w1 = __builtin_amdgcn_cvt_pk_fp8_f32(v.z, v.w, w0, true);
        f8x[i] = (unsigned)w1;
        return;
    }
    if (b == 8192) {                    // init cursors + readout accumulators
        if (t < BG) gcur[t * 16] = t * CAP;
        for (int i = t; i < 2 * BG * HH; i += 256) racc[i] = 0.f;
        return;
    }
    if (b < 8197) { packw_body<64>(W1, pw1, (b - 8193) * 256 + t); return; }
    if (b < 8205) { packw_body<128>(W2, pw2, (b - 8197) * 256 + t); return; }
    // zero csr2 pad region: BG*CAP words = 163840 uint4 = 2560 blocks
    ((uint4*)csr2)[(b - 8205) * 256 + t] = make_uint4(0, 0, 0, 0);
}

// ---------------- pass 1: 32-way partition of edges by graph ----------------
__global__ __launch_bounds__(256) void k_part(const int* __restrict__ src,
                                              const int* __restrict__ dst,
                                              const float* __restrict__ ew,
                                              int* __restrict__ gcur,
                                              uint2* __restrict__ recs) {
    __shared__ int cnt[32];
    __shared__ int start[32];
    __shared__ int gbase[32];
    __shared__ uint2 stage[4096];
    int t = threadIdx.x;
    int ebase = blockIdx.x * 4096;
    if (t < 32) cnt[t] = 0;
    __syncthreads();
    int es[16]; int ed[16]; float ev[16];
#pragma unroll
    for (int k = 0; k < 16; k++) {
        int e = ebase + k * 256 + t;
        es[k] = src[e]; ed[k] = dst[e]; ev[k] = ew[e];
        atomicAdd(&cnt[es[k] >> 12], 1);
    }
    __syncthreads();
    if (t == 0) {
        int run = 0;
        for (int g = 0; g < 32; g++) { start[g] = run; run += cnt[g]; }
    }
    __syncthreads();
    if (t < 32) {
        gbase[t] = atomicAdd(&gcur[t * 16], cnt[t]);
        cnt[t] = start[t];                      // becomes cursor
    }
    __syncthreads();
#pragma unroll
    for (int k = 0; k < 16; k++) {
        int g = es[k] >> 12;
        int pos = atomicAdd(&cnt[g], 1);
        stage[pos] = make_uint2((unsigned)(es[k] & 4095) | ((unsigned)(ed[k] & 4095) << 12) |
                                ((unsigned)g << 24), __float_as_uint(ev[k]));
    }
    __syncthreads();
    for (int i = t; i < 4096; i += 256) {
        uint2 r = stage[i];
        int g = r.x >> 24;
        recs[gbase[g] + (i - start[g])] = r;
    }
}

// ---------------- build phase A: per-(graph,chunk) histograms ----------------
__global__ __launch_bounds__(1024) void k_hist(const uint2* __restrict__ recs,
                                               const int* __restrict__ gcur,
                                               int* __restrict__ shist,
                                               int* __restrict__ dhist) {
    __shared__ int hs[4096];
    __shared__ int hd[4096];
    int t = threadIdx.x;
    int g = blockIdx.x >> 3, c = blockIdx.x & 7;
    int n = gcur[g * 16] - g * CAP;
    int lo = (n * c) >> 3, hi = (n * (c + 1)) >> 3;
    ((int4*)hs)[t] = make_int4(0, 0, 0, 0);
    ((int4*)hd)[t] = make_int4(0, 0, 0, 0);
    __syncthreads();
    const uint2* base = recs + (size_t)g * CAP;
    for (int i = lo + t; i < hi; i += 1024) {
        unsigned x = base[i].x;
        atomicAdd(&hs[x & 4095], 1);
        atomicAdd(&hd[(x >> 12) & 4095], 1);
    }
    __syncthreads();
    ((int4*)(shist + (size_t)blockIdx.x * 4096))[t] = ((int4*)hs)[t];
    ((int4*)(dhist + (size_t)blockIdx.x * 4096))[t] = ((int4*)hd)[t];
}

// ---------------- build phase B: degrees, rsqrt, padded offsets, chunk cursor bases ----------------
__global__ __launch_bounds__(1024) void k_offs(int* __restrict__ shist,
                                               int* __restrict__ dhist,
                                               float* __restrict__ rs_s,
                                               float* __restrict__ rsd,
                                               int* __restrict__ degd,
                                               int* __restrict__ offs) {
    __shared__ int partial[1024];
    int t = threadIdx.x, g = blockIdx.x;
    int sdeg[4] = {0, 0, 0, 0}, ddeg[4] = {0, 0, 0, 0};
#pragma unroll
    for (int c = 0; c < 8; c++) {
        int4 sv = ((const int4*)(shist + (size_t)(g * 8 + c) * 4096))[t];
        int4 dv = ((const int4*)(dhist + (size_t)(g * 8 + c) * 4096))[t];
        sdeg[0] += sv.x; sdeg[1] += sv.y; sdeg[2] += sv.z; sdeg[3] += sv.w;
        ddeg[0] += dv.x; ddeg[1] += dv.y; ddeg[2] += dv.z; ddeg[3] += dv.w;
    }
    int pdeg[4];
#pragma unroll
    for (int j = 0; j < 4; j++) {
        int idx = t * 4 + j;
        int vs = sdeg[j]; if (vs < 1) vs = 1;
        rs_s[g * PP + idx] = rsqrtf((float)vs);
        int vd = ddeg[j]; if (vd < 1) vd = 1;
        rsd[g * PP + idx]  = rsqrtf((float)vd);
        pdeg[j] = (ddeg[j] + 3) & ~3;           // padded to multiple of 4
        degd[g * PP + idx] = pdeg[j];           // agg loops run over padded count
    }
    partial[t] = pdeg[0] + pdeg[1] + pdeg[2] + pdeg[3];
    __syncthreads();
    for (int off = 1; off < 1024; off <<= 1) {
        int v = partial[t];
        int add = (t >= off) ? partial[t - off] : 0;
        __syncthreads();
        partial[t] = v + add;
        __syncthreads();
    }
    int run = (t == 0) ? 0 : partial[t - 1];
#pragma unroll
    for (int j = 0; j < 4; j++) {
        int idx = t * 4 + j;
        offs[g * PP + idx] = g * CAP + run;
        int nb = run;                           // true edges placed at segment start
        for (int c = 0; c < 8; c++) {
            size_t hidx = (size_t)(g * 8 + c) * 4096 + idx;
            int v = dhist[hidx];
            dhist[hidx] = nb;                   // per-chunk cursor base (graph-relative)
            nb += v;
        }
        run += pdeg[j];                         // pad region stays zero
    }
}

// ---------------- build phase C: counting-sort placement ----------------
__global__ __launch_bounds__(1024) void k_place(const uint2* __restrict__ recs,
                                                const int* __restrict__ gcur,
                                                const int* __restrict__ dhist,
                                                const float* __restrict__ rs_s,
                                                unsigned* __restrict__ csr2) {
    __shared__ int cur[4096];
    __shared__ float rss[4096];
    int t = threadIdx.x;
    int g = blockIdx.x >> 3, c = blockIdx.x & 7;
    int n = gcur[g * 16] - g * CAP;
    int lo = (n * c) >> 3, hi = (n * (c + 1)) >> 3;
    ((int4*)cur)[t] = ((const int4*)(dhist + (size_t)blockIdx.x * 4096))[t];
    ((float4*)rss)[t] = ((const float4*)(rs_s + (size_t)g * PP))[t];
    __syncthreads();
    const uint2* base = recs + (size_t)g * CAP;
    unsigned* cbase = csr2 + (size_t)g * CAP;
    for (int i = lo + t; i < hi; i += 1024) {
        uint2 r = base[i];
        int sl = r.x & 4095, dl = (r.x >> 12) & 4095;
        int pos = atomicAdd(&cur[dl], 1);
        float wf = __uint_as_float(r.y) * rss[sl];
        cbase[pos] = (unsigned)sl | ((unsigned)__half_as_ushort(__float2half(wf)) << 16);
    }
}

// ---------------- fp8 edge accumulation primitives ----------------
// edge word: sl(12b) | half-weight<<16; fp8 word q = 4 feats; accumulate f32x2 (v_pk_fma_f32)
__device__ __forceinline__ void eacc8(unsigned rec, unsigned q, f32x2& P01, f32x2& P23) {
    f32x2 lo = __builtin_amdgcn_cvt_pk_f32_fp8((int)q, false);
    f32x2 hi = __builtin_amdgcn_cvt_pk_f32_fp8((int)q, true);
    float w = w16(rec);
    P01 += lo * w;
    P23 += hi * w;
}

template <int ROWW>   // fp8 row width in words: 16 (64 feats) or 32 (128 feats)
__device__ __forceinline__ void gath8(const unsigned* __restrict__ hp, u32x4 r,
                                      unsigned& d0, unsigned& d1, unsigned& d2, unsigned& d3) {
    d0 = hp[(r[0] & 4095u) * ROWW];
    d1 = hp[(r[1] & 4095u) * ROWW];
    d2 = hp[(r[2] & 4095u) * ROWW];
    d3 = hp[(r[3] & 4095u) * ROWW];
}

__device__ __forceinline__ void macc8(u32x4 r, unsigned q0, unsigned q1, unsigned q2, unsigned q3,
                                      f32x2& P01, f32x2& P23) {
    eacc8(r[0], q0, P01, P23); eacc8(r[1], q1, P01, P23);
    eacc8(r[2], q2, P01, P23); eacc8(r[3], q3, P01, P23);
}

// ---------------- dual-node fp8 aggregation, 2-deep ping-pong gather pipeline ----------------
// csr2 reads nontemporal (streamed once; keep L2 for the gather table).
// Pipeline may read one csr2 quad past a segment end: csr2 slack region is zeroed and
// row indices are masked, so such loads are safe and their data never enters macc.
template <int ROWW>
__device__ __forceinline__ void agg_dual8(const unsigned* __restrict__ hp,
                                          const u32x4* __restrict__ cs4,
                                          int oa, int ca, int ob, int cb,
                                          f32x2& A01, f32x2& A23, f32x2& B01, f32x2& B23) {
    f32x2 z = {0.f, 0.f};
    A01 = z; A23 = z; B01 = z; B23 = z;
    unsigned a4 = ((unsigned)oa) >> 2, b4 = ((unsigned)ob) >> 2;
    int c0 = ca < cb ? ca : cb;
    int cm = ca < cb ? cb : ca;
    int nq = c0 >> 2;
    if (nq > 0) {
        u32x4 ra0 = __builtin_nontemporal_load(cs4 + a4);
        u32x4 rb0 = __builtin_nontemporal_load(cs4 + b4);
        u32x4 ra1 = __builtin_nontemporal_load(cs4 + a4 + 1);
        u32x4 rb1 = __builtin_nontemporal_load(cs4 + b4 + 1);
        unsigned A0, A1, A2, A3, B0, B1, B2, B3;
        unsigned C0, C1, C2, C3, D0, D1, D2, D3;
        gath8<ROWW>(hp, ra0, A0, A1, A2, A3);
        gath8<ROWW>(hp, rb0, B0, B1, B2, B3);
        int k = 0;
        for (; k + 2 <= nq; k += 2) {
            gath8<ROWW>(hp, ra1, C0, C1, C2, C3);            // issue quad k+1 gathers
            gath8<ROWW>(hp, rb1, D0, D1, D2, D3);
            u32x4 ra2 = __builtin_nontemporal_load(cs4 + a4 + k + 2);
            u32x4 rb2 = __builtin_nontemporal_load(cs4 + b4 + k + 2);
            macc8(ra0, A0, A1, A2, A3, A01, A23);            // math on quad k
            macc8(rb0, B0, B1, B2, B3, B01, B23);
            gath8<ROWW>(hp, ra2, A0, A1, A2, A3);            // issue quad k+2 gathers
            gath8<ROWW>(hp, rb2, B0, B1, B2, B3);
            u32x4 ra3 = __builtin_nontemporal_load(cs4 + a4 + k + 3);
            u32x4 rb3 = __builtin_nontemporal_load(cs4 + b4 + k + 3);
            macc8(ra1, C0, C1, C2, C3, A01, A23);            // math on quad k+1
            macc8(rb1, D0, D1, D2, D3, B01, B23);
            ra0 = ra2; rb0 = rb2; ra1 = ra3; rb1 = rb3;
        }
        if (k < nq) {                                         // odd leftover quad
            macc8(ra0, A0, A1, A2, A3, A01, A23);
            macc8(rb0, B0, B1, B2, B3, B01, B23);
        }
    }
    if (cm > c0) {                               // remainder: one node has extra quads
        bool an = ca > cb;
        unsigned t4 = an ? a4 : b4;
        int kq1 = cm >> 2, nq0 = c0 >> 2;
        f32x2 E01 = z, E23 = z;
        u32x4 rr = __builtin_nontemporal_load(cs4 + t4 + nq0);
        for (int k = nq0; k < kq1; k++) {
            unsigned q0, q1, q2, q3;
            gath8<ROWW>(hp, rr, q0, q1, q2, q3);
            u32x4 nr = __builtin_nontemporal_load(cs4 + t4 + k + 1);
            macc8(rr, q0, q1, q2, q3, E01, E23);
            rr = nr;
        }
        if (an) { A01 += E01; A23 += E23; }
        else    { B01 += E01; B23 += E23; }
    }
}

// ================= FUSED layer 1: fp8 gather (quarter-wave/node, dual-node) -> LDS -> MFMA =================
__global__ __launch_bounds__(256) void k_aggemm1(const unsigned* __restrict__ f8x,  // [NN*16] fp8 words
                                                 const unsigned* __restrict__ csr2,
                                                 const int* __restrict__ offs,
                                                 const int* __restrict__ degd,
                                                 const float* __restrict__ rsd,
                                                 const short* __restrict__ PW,
                                                 unsigned short* __restrict__ C,
                                                 float* __restrict__ part) {
    constexpr int WP = 36;                       // padded row stride (words); 144 B, 16B-aligned
    __shared__ unsigned lds[64 * WP];            // 9.2 KB
    __shared__ float s1[HH], s2[HH];
    int t = threadIdx.x;
    if (t < HH) { s1[t] = 0.f; s2[t] = 0.f; }
    int bid = blockIdx.x;                        // 2048 blocks
    int xcd = bid & 7, idx = bid >> 3;           // idx 0..255
    int g = xcd * 4 + (idx >> 6);                // XCD x owns graphs 4x..4x+3
    int node0 = g * PP + (idx & 63) * 64;        // 64 nodes per block, one graph
    int lane = t & 63, wv = t >> 6;
    int q = lane >> 4, ql = lane & 15;           // quarter-wave covers a 16-word fp8 row
    const unsigned* hp8 = f8x + (size_t)((unsigned)(g * PP)) * 16 + ql;
    const u32x4* cs4 = (const u32x4*)csr2;
#pragma unroll
    for (int p = 0; p < 2; p++) {                // per pass: quarter handles nodes va, va+1
        int lrA = wv * 16 + p * 8 + q * 2;       // local row
        int va = node0 + lrA;
        int2 oo = *(const int2*)(offs + va);
        int2 dd = *(const int2*)(degd + va);     // counts % 4 == 0
        f32x2 A01, A23, B01, B23;
        agg_dual8<16>(hp8, cs4, oo.x, dd.x, oo.y, dd.y, A01, A23, B01, B23);
        float2 rr2 = *(const float2*)(rsd + va);
        *(uint2*)&lds[lrA * WP + ql * 2] =
            make_uint2(pack2bf(A01.x * rr2.x, A01.y * rr2.x),
                       pack2bf(A23.x * rr2.x, A23.y * rr2.x));
        *(uint2*)&lds[(lrA + 1) * WP + ql * 2] =
            make_uint2(pack2bf(B01.x * rr2.y, B01.y * rr2.y),
                       pack2bf(B23.x * rr2.y, B23.y * rr2.y));
    }
    __syncthreads();
    // MFMA: wave wv -> local rows wv*16..+15, K=64
    int m = lane & 15, quad = lane >> 4;
    bf16x8 a[2];
#pragma unroll
    for (int kt = 0; kt < 2; kt++)
        a[kt] = *(const bf16x8*)&lds[(wv * 16 + m) * WP + kt * 16 + quad * 4];
#pragma unroll
    for (int nt = 0; nt < 8; nt++) {
        f32x4 acc = {0.f, 0.f, 0.f, 0.f};
#pragma unroll
        for (int kt = 0; kt < 2; kt++) {
            bf16x8 b = *(const bf16x8*)(PW + ((size_t)(kt * 8 + nt) * 64 + lane) * 8);
            acc = __builtin_amdgcn_mfma_f32_16x16x32_bf16(a[kt], b, acc, 0, 0, 0);
        }
        int col = nt * 16 + m;
        int r0 = node0 + wv * 16 + quad * 4;
        float ps = 0.f, pq = 0.f;
#pragma unroll
        for (int r = 0; r < 4; r++) {
            C[(size_t)(r0 + r) * HH + col] = (unsigned short)f2bf(acc[r]);
            ps += acc[r]; pq += acc[r] * acc[r];
        }
        atomicAdd(&s1[col], ps);
        atomicAdd(&s2[col], pq);
    }
    __syncthreads();
    if (t < HH) {
        part[bid * 256 + t]      = s1[t];
        part[bid * 256 + HH + t] = s2[t];
    }
}

// ================= FUSED layer 2: fp8 gather (half-wave/node, dual-node) -> LDS -> MFMA =================
__global__ __launch_bounds__(256) void k_aggemm2(const unsigned* __restrict__ f8,   // [NN*32] fp8 words
                                                 const unsigned* __restrict__ csr2,
                                                 const int* __restrict__ offs,
                                                 const int* __restrict__ degd,
                                                 const float* __restrict__ rsd,
                                                 const short* __restrict__ PW,
                                                 unsigned short* __restrict__ C,
                                                 float* __restrict__ part) {
    constexpr int WP = 68;                       // padded row stride (words); 68%4==0
    __shared__ unsigned lds[64 * WP];            // 17.4 KB
    __shared__ float s1[HH], s2[HH];
    int t = threadIdx.x;
    if (t < HH) { s1[t] = 0.f; s2[t] = 0.f; }
    int bid = blockIdx.x;                        // 2048 blocks
    int xcd = bid & 7, idx = bid >> 3;
    int g = xcd * 4 + (idx >> 6);
    int node0 = g * PP + (idx & 63) * 64;
    int lane = t & 63, wv = t >> 6;
    int half = lane >> 5, sl = lane & 31;
    // fp8 row = 32 words; lane sl covers feats 4sl..4sl+3
    const unsigned* hp8 = f8 + (size_t)((unsigned)(g * PP)) * 32 + sl;
    const u32x4* cs4 = (const u32x4*)csr2;
#pragma unroll
    for (int p = 0; p < 4; p++) {                // per pass: half-wave handles nodes va, va+1
        int lrA = wv * 16 + p * 4 + half * 2;
        int va = node0 + lrA;
        int2 oo = *(const int2*)(offs + va);
        int2 dd = *(const int2*)(degd + va);     // counts % 4 == 0
        f32x2 A01, A23, B01, B23;
        agg_dual8<32>(hp8, cs4, oo.x, dd.x, oo.y, dd.y, A01, A23, B01, B23);
        float2 rr2 = *(const float2*)(rsd + va);
        *(uint2*)&lds[lrA * WP + sl * 2] =
            make_uint2(pack2bf(A01.x * rr2.x, A01.y * rr2.x),
                       pack2bf(A23.x * rr2.x, A23.y * rr2.x));
        *(uint2*)&lds[(lrA + 1) * WP + sl * 2] =
            make_uint2(pack2bf(B01.x * rr2.y, B01.y * rr2.y),
                       pack2bf(B23.x * rr2.y, B23.y * rr2.y));
    }
    __syncthreads();
    // MFMA: wave wv -> local rows wv*16..+15, K=128
    int m = lane & 15, quad = lane >> 4;
    bf16x8 a[4];
#pragma unroll
    for (int kt = 0; kt < 4; kt++)
        a[kt] = *(const bf16x8*)&lds[(wv * 16 + m) * WP + kt * 16 + quad * 4];
#pragma unroll
    for (int nt = 0; nt < 8; nt++) {
        f32x4 acc = {0.f, 0.f, 0.f, 0.f};
#pragma unroll
        for (int kt = 0; kt < 4; kt++) {
            bf16x8 b = *(const bf16x8*)(PW + ((size_t)(kt * 8 + nt) * 64 + lane) * 8);
            acc = __builtin_amdgcn_mfma_f32_16x16x32_bf16(a[kt], b, acc, 0, 0, 0);
        }
        int col = nt * 16 + m;
        int r0 = node0 + wv * 16 + quad * 4;
        float ps = 0.f, pq = 0.f;
#pragma unroll
        for (int r = 0; r < 4; r++) {
            C[(size_t)(r0 + r) * HH + col] = (unsigned short)f2bf(acc[r]);
            ps += acc[r]; pq += acc[r] * acc[r];
        }
        atomicAdd(&s1[col], ps);
        atomicAdd(&s2[col], pq);
    }
    __syncthreads();
    if (t < HH) {
        part[bid * 256 + t]      = s1[t];
        part[bid * 256 + HH + t] = s2[t];
    }
}

// ---------------- stage-1 reduction of gemm partials ----------------
__global__ __launch_bounds__(256) void k_red(const float* __restrict__ part,
                                             float* __restrict__ pb) {
    int t = threadIdx.x, b = blockIdx.x;        // 64 blocks
    float s = 0.f;
    for (int r = 0; r < 32; r++) s += part[(size_t)(b * 32 + r) * 256 + t];
    pb[b * 256 + t] = s;
}

// ---------------- reduce + norm coefficients ----------------
__global__ void k_coef(const float* __restrict__ pb, const float* __restrict__ gamma,
                       const float* __restrict__ beta, const float* __restrict__ alpha,
                       float* __restrict__ ab) {
    int t = threadIdx.x;                         // 256 threads
    float s = 0.f;
    for (int b = 0; b < 64; b++) s += pb[b * 256 + t];
    __shared__ float sh[256];
    sh[t] = s;
    __syncthreads();
    if (t < 128) {
        float mu = sh[t] * (1.f / NN);
        float e2 = sh[128 + t] * (1.f / NN);
        float al = alpha[t];
        float var = e2 - (2.f * al - al * al) * mu * mu;
        float a = rsqrtf(var + EPSV) * gamma[t];
        ab[t] = a;
        ab[HH + t] = beta[t] - al * mu * a;
    }
}

// ---------------- fused norm + leaky-relu (+fp8 h1 emit) + per-graph readout ----------------
template <bool WRITE>
__global__ __launch_bounds__(256) void k_normro(const unsigned* __restrict__ h,  // bf16 pairs
                                                const float* __restrict__ ab,
                                                float* __restrict__ racc,
                                                unsigned short* __restrict__ f8) {
    int fp = threadIdx.x & 63;                   // feature pair
    int q  = threadIdx.x >> 6;                   // 0..3
    int node0 = blockIdx.x * 64;                 // one graph per block
    int g = node0 / PP;
    float a0 = ab[2 * fp], a1 = ab[2 * fp + 1];
    float b0 = ab[HH + 2 * fp], b1 = ab[HH + 2 * fp + 1];
    float s0 = 0.f, s1 = 0.f;
    for (int i = q; i < 64; i += 4) {
        size_t idx = (size_t)(node0 + i) * 64 + fp;
        unsigned v = h[idx];
        float x0 = fmaf(a0, bflo(v), b0); x0 = x0 > 0.f ? x0 : SLOPEV * x0;
        float x1 = fmaf(a1, bfhi(v), b1); x1 = x1 > 0.f ? x1 : SLOPEV * x1;
        if (WRITE) f8[idx] = (unsigned short)__builtin_amdgcn_cvt_pk_fp8_f32(x0, x1, 0, false);
        s0 += x0; s1 += x1;
    }
    __shared__ float sh[512];
    sh[threadIdx.x] = s0;
    sh[256 + threadIdx.x] = s1;
    __syncthreads();
    if (q == 0) {
        float t0 = s0 + sh[64 + fp] + sh[128 + fp] + sh[192 + fp];
        float t1 = s1 + sh[256 + 64 + fp] + sh[256 + 128 + fp] + sh[256 + 192 + fp];
        atomicAdd(&racc[g * HH + 2 * fp],     t0);
        atomicAdd(&racc[g * HH + 2 * fp + 1], t1);
    }
}

// ---------------- final head ----------------
__global__ void k_final(const float* __restrict__ racc1, const float* __restrict__ racc2,
                        const float* __restrict__ Wc, float* __restrict__ out) {
    int t = threadIdx.x;                         // 512 = 32*16
    int b = t >> 4, o = t & 15;
    float acc = 0.f;
    for (int f = 0; f < HH; f++) acc += racc1[b * HH + f] * Wc[o * (2 * HH) + f];
    for (int f = 0; f < HH; f++) acc += racc2[b * HH + f] * Wc[o * (2 * HH) + HH + f];
    out[t] = acc * (1.f / PP);
}

extern "C" void kernel_launch(void* const* d_in, const int* in_sizes, int n_in,
                              void* d_out, int out_size, void* d_ws, size_t ws_size,
                              hipStream_t stream) {
    const float* features = (const float*)d_in[0];
    const float* ew       = (const float*)d_in[1];
    const int*   src      = (const int*)d_in[2];
    const int*   dst      = (const int*)d_in[3];
    const float* W1       = (const float*)d_in[4];
    const float* W2       = (const float*)d_in[5];
    const float* Wc       = (const float*)d_in[6];
    const float* gamma1   = (const float*)d_in[7];
    const float* beta1    = (const float*)d_in[8];
    const float* alpha1   = (const float*)d_in[9];
    const float* gamma2   = (const float*)d_in[10];
    const float* beta2    = (const float*)d_in[11];
    const float* alpha2   = (const float*)d_in[12];
    float* out = (float*)d_out;

    char* w = (char*)d_ws;
    // misc block [0, 1 MB)
    int*    gcur   = (int*)(w + 0);                         // 32 * 16 ints
    float*  racc1  = (float*)(w + (16u << 10));             // 16 KB
    float*  racc2  = (float*)(w + (32u << 10));             // contiguous with racc1
    float*  ab1    = (float*)(w + (48u << 10));
    float*  ab2    = (float*)(w + (52u << 10));
    unsigned short* pw1 = (unsigned short*)(w + (64u << 10));   // 16 KB
    unsigned short* pw2 = (unsigned short*)(w + (80u << 10));   // 32 KB
    float*  pb     = (float*)(w + (128u << 10));            // 64 KB
    // arrays
    float*  rs_s   = (float*)(w + (1024u << 10));           // 512 KB
    float*  rsd    = (float*)(w + (1536u << 10));           // 512 KB
    int*    degd   = (int*)(w + (2048u << 10));             // 512 KB
    int*    offs   = (int*)(w + (2560u << 10));             // 512 KB
    float*  part   = (float*)(w + (3u << 20));              // 2 MB: 3..5
    int*    shist  = (int*)(w + (5u << 20));                // 4 MB: 5..9
    int*    dhist  = (int*)(w + (9u << 20));                // 4 MB: 9..13
    unsigned* csr2 = (unsigned*)(w + (13u << 20));          // 10 MB: 13..23
    unsigned* mbuf = (unsigned*)(w + (23u << 20));          // 32 MB: 23..55 (h2pre)
    unsigned* hbuf = (unsigned*)(w + (55u << 20));          // 32 MB: 55..87 (h1pre)
    uint2*    recs = (uint2*)(w + (87u << 20));             // 20 MB: 87..107
    unsigned* f8x  = (unsigned*)(w + (107u << 20));         // 8 MB: 107..115 (features fp8)
    unsigned* f8buf= (unsigned*)(w + (123u << 20));         // 16 MB: 123..139 (h1 fp8)

    // prep (feature->fp8 + init + packw + csr2 zero, fused)
    k_prep<<<10765, 256, 0, stream>>>(features, f8x, W1, pw1, W2, pw2, gcur, racc1, csr2);

    // CSR build
    k_part<<<EE / 4096, 256, 0, stream>>>(src, dst, ew, gcur, recs);
    k_hist<<<BG * 8, 1024, 0, stream>>>(recs, gcur, shist, dhist);
    k_offs<<<BG, 1024, 0, stream>>>(shist, dhist, rs_s, rsd, degd, offs);
    k_place<<<BG * 8, 1024, 0, stream>>>(recs, gcur, dhist, rs_s, csr2);

    // ---- layer 1 (fused agg+gemm; gathers fp8 features) ----
    k_aggemm1<<<NN / 64, 256, 0, stream>>>(f8x, csr2, offs, degd, rsd,
                                           (const short*)pw1, (unsigned short*)hbuf, part);
    k_red<<<64, 256, 0, stream>>>(part, pb);
    k_coef<<<1, 256, 0, stream>>>(pb, gamma1, beta1, alpha1, ab1);
    k_normro<true><<<NN / 64, 256, 0, stream>>>(hbuf, ab1, racc1, (unsigned short*)f8buf);

    // ---- layer 2 (fused agg+gemm; gathers fp8 h1, writes mbuf) ----
    k_aggemm2<<<NN / 64, 256, 0, stream>>>(f8buf, csr2, offs, degd, rsd,
                                           (const short*)pw2, (unsigned short*)mbuf, part);
    k_red<<<64, 256, 0, stream>>>(part, pb);
    k_coef<<<1, 256, 0, stream>>>(pb, gamma2, beta2, alpha2, ab2);
    k_normro<false><<<NN / 64, 256, 0, stream>>>(mbuf, ab2, racc2, nullptr);

    // ---- head ----
    k_final<<<1, 512, 0, stream>>>(racc1, racc2, Wc, out);
}

// Round 4
// 358.928 us; speedup vs baseline: 1.1685x; 1.0328x over previous
//
#include <hip/hip_runtime.h>
#include <hip/hip_fp16.h>

constexpr int NN   = 131072;   // total nodes
constexpr int PP   = 4096;     // nodes per graph
constexpr int BG   = 32;       // graphs
constexpr int EE   = 2097152;  // edges
constexpr int IND  = 64;
constexpr int HH   = 128;
constexpr int CAP  = 81920;    // per-graph slot capacity (65536 mean + pad4 + slack)
constexpr float EPSV   = 1e-5f;
constexpr float SLOPEV = 0.01f;

typedef short bf16x8 __attribute__((ext_vector_type(8)));
typedef float f32x4  __attribute__((ext_vector_type(4)));
typedef float f32x2  __attribute__((ext_vector_type(2)));

__device__ __forceinline__ unsigned f2bf(float f) {
    unsigned u = __float_as_uint(f);
    return (u + 0x7FFFu + ((u >> 16) & 1u)) >> 16;      // RNE
}
__device__ __forceinline__ unsigned pack2bf(float lo, float hi) {
    return f2bf(lo) | (f2bf(hi) << 16);
}
__device__ __forceinline__ float bflo(unsigned p) { return __uint_as_float(p << 16); }
__device__ __forceinline__ float bfhi(unsigned p) { return __uint_as_float(p & 0xFFFF0000u); }
__device__ __forceinline__ float w16(unsigned r) {
    return __half2float(__ushort_as_half((unsigned short)(r >> 16)));
}

// ---------------- W -> MFMA B-fragment prepack (device body) ----------------
template <int K>
__device__ __forceinline__ void packw_body(const float* __restrict__ W,
                                           unsigned short* __restrict__ pw, int t) {
    if (t >= K * 16) return;
    int lane = t & 63, nt = (t >> 6) & 7, kt = t >> 9;
    int kbase = kt * 32 + ((lane >> 4) & 3) * 8;
    int col   = nt * 16 + (lane & 15);
    for (int j = 0; j < 8; j++)
        pw[t * 8 + j] = (unsigned short)f2bf(W[(kbase + j) * HH + col]);
}

// ---------------- fused prep: feature->fp8 cvt + init + weight prepack + csr2 zero ----------------
__global__ __launch_bounds__(256) void k_prep(const float* __restrict__ features,
                                              unsigned* __restrict__ f8x,
                                              const float* __restrict__ W1,
                                              unsigned short* __restrict__ pw1,
                                              const float* __restrict__ W2,
                                              unsigned short* __restrict__ pw2,
                                              int* __restrict__ gcur,
                                              float* __restrict__ racc,
                                              unsigned* __restrict__ csr2) {
    int b = blockIdx.x, t = threadIdx.x;
    if (b < 8192) {                     // fp8 convert: NN*16 = 8192*256 words
        int i = b * 256 + t;
        float4 v = ((const float4*)features)[i];
        int w0 = __builtin_amdgcn_cvt_pk_fp8_f32(v.x, v.y, 0, false);
        int w1 = __builtin_amdgcn_cvt_pk_fp8_f32(v.z, v.w, w0, true);
        f8x[i] = (unsigned)w1;
        return;
    }
    if (b == 8192) {                    // init cursors + readout accumulators
        if (t < BG) gcur[t * 16] = t * CAP;
        for (int i = t; i < 2 * BG * HH; i += 256) racc[i] = 0.f;
        return;
    }
    if (b < 8197) { packw_body<64>(W1, pw1, (b - 8193) * 256 + t); return; }
    if (b < 8205) { packw_body<128>(W2, pw2, (b - 8197) * 256 + t); return; }
    // zero csr2 pad region: BG*CAP words = 163840 uint4 = 2560 blocks
    ((uint4*)csr2)[(b - 8205) * 256 + t] = make_uint4(0, 0, 0, 0);
}

// ---------------- pass 1: 32-way partition of edges by graph ----------------
__global__ __launch_bounds__(256) void k_part(const int* __restrict__ src,
                                              const int* __restrict__ dst,
                                              const float* __restrict__ ew,
                                              int* __restrict__ gcur,
                                              uint2* __restrict__ recs) {
    __shared__ int cnt[32];
    __shared__ int start[32];
    __shared__ int gbase[32];
    __shared__ uint2 stage[4096];
    int t = threadIdx.x;
    int ebase = blockIdx.x * 4096;
    if (t < 32) cnt[t] = 0;
    __syncthreads();
    int es[16]; int ed[16]; float ev[16];
#pragma unroll
    for (int k = 0; k < 16; k++) {
        int e = ebase + k * 256 + t;
        es[k] = src[e]; ed[k] = dst[e]; ev[k] = ew[e];
        atomicAdd(&cnt[es[k] >> 12], 1);
    }
    __syncthreads();
    if (t == 0) {
        int run = 0;
        for (int g = 0; g < 32; g++) { start[g] = run; run += cnt[g]; }
    }
    __syncthreads();
    if (t < 32) {
        gbase[t] = atomicAdd(&gcur[t * 16], cnt[t]);
        cnt[t] = start[t];                      // becomes cursor
    }
    __syncthreads();
#pragma unroll
    for (int k = 0; k < 16; k++) {
        int g = es[k] >> 12;
        int pos = atomicAdd(&cnt[g], 1);
        stage[pos] = make_uint2((unsigned)(es[k] & 4095) | ((unsigned)(ed[k] & 4095) << 12) |
                                ((unsigned)g << 24), __float_as_uint(ev[k]));
    }
    __syncthreads();
    for (int i = t; i < 4096; i += 256) {
        uint2 r = stage[i];
        int g = r.x >> 24;
        recs[gbase[g] + (i - start[g])] = r;
    }
}

// ---------------- build phase A: per-(graph,chunk) histograms ----------------
__global__ __launch_bounds__(1024) void k_hist(const uint2* __restrict__ recs,
                                               const int* __restrict__ gcur,
                                               int* __restrict__ shist,
                                               int* __restrict__ dhist) {
    __shared__ int hs[4096];
    __shared__ int hd[4096];
    int t = threadIdx.x;
    int g = blockIdx.x >> 3, c = blockIdx.x & 7;
    int n = gcur[g * 16] - g * CAP;
    int lo = (n * c) >> 3, hi = (n * (c + 1)) >> 3;
    ((int4*)hs)[t] = make_int4(0, 0, 0, 0);
    ((int4*)hd)[t] = make_int4(0, 0, 0, 0);
    __syncthreads();
    const uint2* base = recs + (size_t)g * CAP;
    for (int i = lo + t; i < hi; i += 1024) {
        unsigned x = base[i].x;
        atomicAdd(&hs[x & 4095], 1);
        atomicAdd(&hd[(x >> 12) & 4095], 1);
    }
    __syncthreads();
    ((int4*)(shist + (size_t)blockIdx.x * 4096))[t] = ((int4*)hs)[t];
    ((int4*)(dhist + (size_t)blockIdx.x * 4096))[t] = ((int4*)hd)[t];
}

// ---------------- build phase B: degrees, rsqrt, padded offsets, chunk cursor bases ----------------
__global__ __launch_bounds__(1024) void k_offs(int* __restrict__ shist,
                                               int* __restrict__ dhist,
                                               float* __restrict__ rs_s,
                                               float* __restrict__ rsd,
                                               int* __restrict__ degd,
                                               int* __restrict__ offs) {
    __shared__ int partial[1024];
    int t = threadIdx.x, g = blockIdx.x;
    int sdeg[4] = {0, 0, 0, 0}, ddeg[4] = {0, 0, 0, 0};
#pragma unroll
    for (int c = 0; c < 8; c++) {
        int4 sv = ((const int4*)(shist + (size_t)(g * 8 + c) * 4096))[t];
        int4 dv = ((const int4*)(dhist + (size_t)(g * 8 + c) * 4096))[t];
        sdeg[0] += sv.x; sdeg[1] += sv.y; sdeg[2] += sv.z; sdeg[3] += sv.w;
        ddeg[0] += dv.x; ddeg[1] += dv.y; ddeg[2] += dv.z; ddeg[3] += dv.w;
    }
    int pdeg[4];
#pragma unroll
    for (int j = 0; j < 4; j++) {
        int idx = t * 4 + j;
        int vs = sdeg[j]; if (vs < 1) vs = 1;
        rs_s[g * PP + idx] = rsqrtf((float)vs);
        int vd = ddeg[j]; if (vd < 1) vd = 1;
        rsd[g * PP + idx]  = rsqrtf((float)vd);
        pdeg[j] = (ddeg[j] + 3) & ~3;           // padded to multiple of 4
        degd[g * PP + idx] = pdeg[j];           // agg loops run over padded count
    }
    partial[t] = pdeg[0] + pdeg[1] + pdeg[2] + pdeg[3];
    __syncthreads();
    for (int off = 1; off < 1024; off <<= 1) {
        int v = partial[t];
        int add = (t >= off) ? partial[t - off] : 0;
        __syncthreads();
        partial[t] = v + add;
        __syncthreads();
    }
    int run = (t == 0) ? 0 : partial[t - 1];
#pragma unroll
    for (int j = 0; j < 4; j++) {
        int idx = t * 4 + j;
        offs[g * PP + idx] = g * CAP + run;
        int nb = run;                           // true edges placed at segment start
        for (int c = 0; c < 8; c++) {
            size_t hidx = (size_t)(g * 8 + c) * 4096 + idx;
            int v = dhist[hidx];
            dhist[hidx] = nb;                   // per-chunk cursor base (graph-relative)
            nb += v;
        }
        run += pdeg[j];                         // pad region stays zero
    }
}

// ---------------- build phase C: counting-sort placement ----------------
__global__ __launch_bounds__(1024) void k_place(const uint2* __restrict__ recs,
                                                const int* __restrict__ gcur,
                                                const int* __restrict__ dhist,
                                                const float* __restrict__ rs_s,
                                                unsigned* __restrict__ csr2) {
    __shared__ int cur[4096];
    __shared__ float rss[4096];
    int t = threadIdx.x;
    int g = blockIdx.x >> 3, c = blockIdx.x & 7;
    int n = gcur[g * 16] - g * CAP;
    int lo = (n * c) >> 3, hi = (n * (c + 1)) >> 3;
    ((int4*)cur)[t] = ((const int4*)(dhist + (size_t)blockIdx.x * 4096))[t];
    ((float4*)rss)[t] = ((const float4*)(rs_s + (size_t)g * PP))[t];
    __syncthreads();
    const uint2* base = recs + (size_t)g * CAP;
    unsigned* cbase = csr2 + (size_t)g * CAP;
    for (int i = lo + t; i < hi; i += 1024) {
        uint2 r = base[i];
        int sl = r.x & 4095, dl = (r.x >> 12) & 4095;
        int pos = atomicAdd(&cur[dl], 1);
        float wf = __uint_as_float(r.y) * rss[sl];
        cbase[pos] = (unsigned)sl | ((unsigned)__half_as_ushort(__float2half(wf)) << 16);
    }
}

// ---------------- fp8 edge accumulation primitives (dwordx2 gathers, pk-f32 accum) ----------------
// edge word: sl(12b) | half-weight<<16; q = uint2 = 8 fp8 feats
__device__ __forceinline__ void eacc2(unsigned rec, uint2 q,
                                      f32x2& P01, f32x2& P23, f32x2& P45, f32x2& P67) {
    f32x2 l0 = __builtin_amdgcn_cvt_pk_f32_fp8((int)q.x, false);
    f32x2 h0 = __builtin_amdgcn_cvt_pk_f32_fp8((int)q.x, true);
    f32x2 l1 = __builtin_amdgcn_cvt_pk_f32_fp8((int)q.y, false);
    f32x2 h1 = __builtin_amdgcn_cvt_pk_f32_fp8((int)q.y, true);
    float w = w16(rec);
    P01 += l0 * w; P23 += h0 * w; P45 += l1 * w; P67 += h1 * w;
}

// ---------------- dual-node fp8 aggregation, R0 control flow, 8-B gathers ----------------
// RW2 = row width in uint2 units (8 for 64-feat layer1, 16 for 128-feat layer2)
template <int RW2>
__device__ __forceinline__ void agg_dual_w(const uint2* __restrict__ hp,
                                           const unsigned* __restrict__ csr2,
                                           int oa, int ca, int ob, int cb,
                                           f32x2& A01, f32x2& A23, f32x2& A45, f32x2& A67,
                                           f32x2& B01, f32x2& B23, f32x2& B45, f32x2& B67) {
    f32x2 z = {0.f, 0.f};
    A01 = z; A23 = z; A45 = z; A67 = z;
    B01 = z; B23 = z; B45 = z; B67 = z;
    int c0 = ca < cb ? ca : cb;
    int cm = ca < cb ? cb : ca;
    int i = 0;
    for (; i < c0; i += 4) {                 // dual-node: 8 dwordx2 gathers in flight
        uint4 ra = *(const uint4*)(csr2 + oa + i);
        uint4 rb = *(const uint4*)(csr2 + ob + i);
        uint2 qa0 = hp[(ra.x & 4095u) * RW2];
        uint2 qa1 = hp[(ra.y & 4095u) * RW2];
        uint2 qa2 = hp[(ra.z & 4095u) * RW2];
        uint2 qa3 = hp[(ra.w & 4095u) * RW2];
        uint2 qb0 = hp[(rb.x & 4095u) * RW2];
        uint2 qb1 = hp[(rb.y & 4095u) * RW2];
        uint2 qb2 = hp[(rb.z & 4095u) * RW2];
        uint2 qb3 = hp[(rb.w & 4095u) * RW2];
        eacc2(ra.x, qa0, A01, A23, A45, A67);
        eacc2(ra.y, qa1, A01, A23, A45, A67);
        eacc2(ra.z, qa2, A01, A23, A45, A67);
        eacc2(ra.w, qa3, A01, A23, A45, A67);
        eacc2(rb.x, qb0, B01, B23, B45, B67);
        eacc2(rb.y, qb1, B01, B23, B45, B67);
        eacc2(rb.z, qb2, B01, B23, B45, B67);
        eacc2(rb.w, qb3, B01, B23, B45, B67);
    }
    if (i < cm) {                            // remainder: one node has extra quads
        int ot = (ca > cb) ? oa : ob;
        f32x2 E01 = z, E23 = z, E45 = z, E67 = z;
        for (; i < cm; i += 4) {
            uint4 rr = *(const uint4*)(csr2 + ot + i);
            uint2 q0 = hp[(rr.x & 4095u) * RW2];
            uint2 q1 = hp[(rr.y & 4095u) * RW2];
            uint2 q2 = hp[(rr.z & 4095u) * RW2];
            uint2 q3 = hp[(rr.w & 4095u) * RW2];
            eacc2(rr.x, q0, E01, E23, E45, E67);
            eacc2(rr.y, q1, E01, E23, E45, E67);
            eacc2(rr.z, q2, E01, E23, E45, E67);
            eacc2(rr.w, q3, E01, E23, E45, E67);
        }
        if (ca > cb) { A01 += E01; A23 += E23; A45 += E45; A67 += E67; }
        else         { B01 += E01; B23 += E23; B45 += E45; B67 += E67; }
    }
}

// ================= FUSED layer 1: fp8 gather (8-lane group/node, dual-node) -> LDS -> MFMA =================
__global__ __launch_bounds__(256) void k_aggemm1(const unsigned* __restrict__ f8x,  // [NN*16] fp8 words
                                                 const unsigned* __restrict__ csr2,
                                                 const int* __restrict__ offs,
                                                 const int* __restrict__ degd,
                                                 const float* __restrict__ rsd,
                                                 const short* __restrict__ PW,
                                                 unsigned short* __restrict__ C,
                                                 float* __restrict__ part) {
    constexpr int WP = 36;                       // padded row stride (words); 144 B, 16B-aligned
    __shared__ unsigned lds[64 * WP];            // 9.2 KB
    __shared__ float s1[HH], s2[HH];
    int t = threadIdx.x;
    if (t < HH) { s1[t] = 0.f; s2[t] = 0.f; }
    int bid = blockIdx.x;                        // 2048 blocks
    int xcd = bid & 7, idx = bid >> 3;           // idx 0..255
    int g = xcd * 4 + (idx >> 6);                // XCD x owns graphs 4x..4x+3
    int node0 = g * PP + (idx & 63) * 64;        // 64 nodes per block, one graph
    int lane = t & 63, wv = t >> 6;
    int grp = lane >> 3, gl = lane & 7;          // 8-lane group covers a 64-B fp8 row
    const uint2* hp = (const uint2*)f8x + (size_t)((unsigned)(g * PP)) * 8 + gl;
    {                                            // one pass: group handles nodes va, va+1
        int lrA = wv * 16 + grp * 2;             // local rows (all 16 covered by 8 groups)
        int va = node0 + lrA;
        int2 oo = *(const int2*)(offs + va);
        int2 dd = *(const int2*)(degd + va);     // counts % 4 == 0
        f32x2 A01, A23, A45, A67, B01, B23, B45, B67;
        agg_dual_w<8>(hp, csr2, oo.x, dd.x, oo.y, dd.y,
                      A01, A23, A45, A67, B01, B23, B45, B67);
        float2 rr2 = *(const float2*)(rsd + va);
        *(uint4*)&lds[lrA * WP + gl * 4] = make_uint4(
            pack2bf(A01.x * rr2.x, A01.y * rr2.x), pack2bf(A23.x * rr2.x, A23.y * rr2.x),
            pack2bf(A45.x * rr2.x, A45.y * rr2.x), pack2bf(A67.x * rr2.x, A67.y * rr2.x));
        *(uint4*)&lds[(lrA + 1) * WP + gl * 4] = make_uint4(
            pack2bf(B01.x * rr2.y, B01.y * rr2.y), pack2bf(B23.x * rr2.y, B23.y * rr2.y),
            pack2bf(B45.x * rr2.y, B45.y * rr2.y), pack2bf(B67.x * rr2.y, B67.y * rr2.y));
    }
    __syncthreads();
    // MFMA: wave wv -> local rows wv*16..+15, K=64
    int m = lane & 15, quad = lane >> 4;
    bf16x8 a[2];
#pragma unroll
    for (int kt = 0; kt < 2; kt++)
        a[kt] = *(const bf16x8*)&lds[(wv * 16 + m) * WP + kt * 16 + quad * 4];
#pragma unroll
    for (int nt = 0; nt < 8; nt++) {
        f32x4 acc = {0.f, 0.f, 0.f, 0.f};
#pragma unroll
        for (int kt = 0; kt < 2; kt++) {
            bf16x8 b = *(const bf16x8*)(PW + ((size_t)(kt * 8 + nt) * 64 + lane) * 8);
            acc = __builtin_amdgcn_mfma_f32_16x16x32_bf16(a[kt], b, acc, 0, 0, 0);
        }
        int col = nt * 16 + m;
        int r0 = node0 + wv * 16 + quad * 4;
        float ps = 0.f, pq = 0.f;
#pragma unroll
        for (int r = 0; r < 4; r++) {
            C[(size_t)(r0 + r) * HH + col] = (unsigned short)f2bf(acc[r]);
            ps += acc[r]; pq += acc[r] * acc[r];
        }
        atomicAdd(&s1[col], ps);
        atomicAdd(&s2[col], pq);
    }
    __syncthreads();
    if (t < HH) {
        part[bid * 256 + t]      = s1[t];
        part[bid * 256 + HH + t] = s2[t];
    }
}

// ================= FUSED layer 2: fp8 gather (16-lane group/node, dual-node) -> LDS -> MFMA =================
__global__ __launch_bounds__(256) void k_aggemm2(const unsigned* __restrict__ f8,   // [NN*32] fp8 words
                                                 const unsigned* __restrict__ csr2,
                                                 const int* __restrict__ offs,
                                                 const int* __restrict__ degd,
                                                 const float* __restrict__ rsd,
                                                 const short* __restrict__ PW,
                                                 unsigned short* __restrict__ C,
                                                 float* __restrict__ part) {
    constexpr int WP = 68;                       // padded row stride (words); 272 B = 17*16
    __shared__ unsigned lds[64 * WP];            // 17.4 KB
    __shared__ float s1[HH], s2[HH];
    int t = threadIdx.x;
    if (t < HH) { s1[t] = 0.f; s2[t] = 0.f; }
    int bid = blockIdx.x;                        // 2048 blocks
    int xcd = bid & 7, idx = bid >> 3;
    int g = xcd * 4 + (idx >> 6);
    int node0 = g * PP + (idx & 63) * 64;
    int lane = t & 63, wv = t >> 6;
    int grp = lane >> 4, gl = lane & 15;         // 16-lane group covers a 128-B fp8 row
    const uint2* hp = (const uint2*)f8 + (size_t)((unsigned)(g * PP)) * 16 + gl;
    for (int p = 0; p < 2; p++) {                // per pass: group handles nodes va, va+1
        int lrA = wv * 16 + p * 8 + grp * 2;
        int va = node0 + lrA;
        int2 oo = *(const int2*)(offs + va);
        int2 dd = *(const int2*)(degd + va);     // counts % 4 == 0
        f32x2 A01, A23, A45, A67, B01, B23, B45, B67;
        agg_dual_w<16>(hp, csr2, oo.x, dd.x, oo.y, dd.y,
                       A01, A23, A45, A67, B01, B23, B45, B67);
        float2 rr2 = *(const float2*)(rsd + va);
        *(uint4*)&lds[lrA * WP + gl * 4] = make_uint4(
            pack2bf(A01.x * rr2.x, A01.y * rr2.x), pack2bf(A23.x * rr2.x, A23.y * rr2.x),
            pack2bf(A45.x * rr2.x, A45.y * rr2.x), pack2bf(A67.x * rr2.x, A67.y * rr2.x));
        *(uint4*)&lds[(lrA + 1) * WP + gl * 4] = make_uint4(
            pack2bf(B01.x * rr2.y, B01.y * rr2.y), pack2bf(B23.x * rr2.y, B23.y * rr2.y),
            pack2bf(B45.x * rr2.y, B45.y * rr2.y), pack2bf(B67.x * rr2.y, B67.y * rr2.y));
    }
    __syncthreads();
    // MFMA: wave wv -> local rows wv*16..+15, K=128
    int m = lane & 15, quad = lane >> 4;
    bf16x8 a[4];
#pragma unroll
    for (int kt = 0; kt < 4; kt++)
        a[kt] = *(const bf16x8*)&lds[(wv * 16 + m) * WP + kt * 16 + quad * 4];
#pragma unroll
    for (int nt = 0; nt < 8; nt++) {
        f32x4 acc = {0.f, 0.f, 0.f, 0.f};
#pragma unroll
        for (int kt = 0; kt < 4; kt++) {
            bf16x8 b = *(const bf16x8*)(PW + ((size_t)(kt * 8 + nt) * 64 + lane) * 8);
            acc = __builtin_amdgcn_mfma_f32_16x16x32_bf16(a[kt], b, acc, 0, 0, 0);
        }
        int col = nt * 16 + m;
        int r0 = node0 + wv * 16 + quad * 4;
        float ps = 0.f, pq = 0.f;
#pragma unroll
        for (int r = 0; r < 4; r++) {
            C[(size_t)(r0 + r) * HH + col] = (unsigned short)f2bf(acc[r]);
            ps += acc[r]; pq += acc[r] * acc[r];
        }
        atomicAdd(&s1[col], ps);
        atomicAdd(&s2[col], pq);
    }
    __syncthreads();
    if (t < HH) {
        part[bid * 256 + t]      = s1[t];
        part[bid * 256 + HH + t] = s2[t];
    }
}

// ---------------- stage-1 reduction of gemm partials ----------------
__global__ __launch_bounds__(256) void k_red(const float* __restrict__ part,
                                             float* __restrict__ pb) {
    int t = threadIdx.x, b = blockIdx.x;        // 64 blocks
    float s = 0.f;
    for (int r = 0; r < 32; r++) s += part[(size_t)(b * 32 + r) * 256 + t];
    pb[b * 256 + t] = s;
}

// ---------------- reduce + norm coefficients ----------------
__global__ void k_coef(const float* __restrict__ pb, const float* __restrict__ gamma,
                       const float* __restrict__ beta, const float* __restrict__ alpha,
                       float* __restrict__ ab) {
    int t = threadIdx.x;                         // 256 threads
    float s = 0.f;
    for (int b = 0; b < 64; b++) s += pb[b * 256 + t];
    __shared__ float sh[256];
    sh[t] = s;
    __syncthreads();
    if (t < 128) {
        float mu = sh[t] * (1.f / NN);
        float e2 = sh[128 + t] * (1.f / NN);
        float al = alpha[t];
        float var = e2 - (2.f * al - al * al) * mu * mu;
        float a = rsqrtf(var + EPSV) * gamma[t];
        ab[t] = a;
        ab[HH + t] = beta[t] - al * mu * a;
    }
}

// ---------------- fused norm + leaky-relu (+fp8 h1 emit) + per-graph readout ----------------
template <bool WRITE>
__global__ __launch_bounds__(256) void k_normro(const unsigned* __restrict__ h,  // bf16 pairs
                                                const float* __restrict__ ab,
                                                float* __restrict__ racc,
                                                unsigned short* __restrict__ f8) {
    int fp = threadIdx.x & 63;                   // feature pair
    int q  = threadIdx.x >> 6;                   // 0..3
    int node0 = blockIdx.x * 64;                 // one graph per block
    int g = node0 / PP;
    float a0 = ab[2 * fp], a1 = ab[2 * fp + 1];
    float b0 = ab[HH + 2 * fp], b1 = ab[HH + 2 * fp + 1];
    float s0 = 0.f, s1 = 0.f;
    for (int i = q; i < 64; i += 4) {
        size_t idx = (size_t)(node0 + i) * 64 + fp;
        unsigned v = h[idx];
        float x0 = fmaf(a0, bflo(v), b0); x0 = x0 > 0.f ? x0 : SLOPEV * x0;
        float x1 = fmaf(a1, bfhi(v), b1); x1 = x1 > 0.f ? x1 : SLOPEV * x1;
        if (WRITE) f8[idx] = (unsigned short)__builtin_amdgcn_cvt_pk_fp8_f32(x0, x1, 0, false);
        s0 += x0; s1 += x1;
    }
    __shared__ float sh[512];
    sh[threadIdx.x] = s0;
    sh[256 + threadIdx.x] = s1;
    __syncthreads();
    if (q == 0) {
        float t0 = s0 + sh[64 + fp] + sh[128 + fp] + sh[192 + fp];
        float t1 = s1 + sh[256 + 64 + fp] + sh[256 + 128 + fp] + sh[256 + 192 + fp];
        atomicAdd(&racc[g * HH + 2 * fp],     t0);
        atomicAdd(&racc[g * HH + 2 * fp + 1], t1);
    }
}

// ---------------- final head ----------------
__global__ void k_final(const float* __restrict__ racc1, const float* __restrict__ racc2,
                        const float* __restrict__ Wc, float* __restrict__ out) {
    int t = threadIdx.x;                         // 512 = 32*16
    int b = t >> 4, o = t & 15;
    float acc = 0.f;
    for (int f = 0; f < HH; f++) acc += racc1[b * HH + f] * Wc[o * (2 * HH) + f];
    for (int f = 0; f < HH; f++) acc += racc2[b * HH + f] * Wc[o * (2 * HH) + HH + f];
    out[t] = acc * (1.f / PP);
}

extern "C" void kernel_launch(void* const* d_in, const int* in_sizes, int n_in,
                              void* d_out, int out_size, void* d_ws, size_t ws_size,
                              hipStream_t stream) {
    const float* features = (const float*)d_in[0];
    const float* ew       = (const float*)d_in[1];
    const int*   src      = (const int*)d_in[2];
    const int*   dst      = (const int*)d_in[3];
    const float* W1       = (const float*)d_in[4];
    const float* W2       = (const float*)d_in[5];
    const float* Wc       = (const float*)d_in[6];
    const float* gamma1   = (const float*)d_in[7];
    const float* beta1    = (const float*)d_in[8];
    const float* alpha1   = (const float*)d_in[9];
    const float* gamma2   = (const float*)d_in[10];
    const float* beta2    = (const float*)d_in[11];
    const float* alpha2   = (const float*)d_in[12];
    float* out = (float*)d_out;

    char* w = (char*)d_ws;
    // misc block [0, 1 MB)
    int*    gcur   = (int*)(w + 0);                         // 32 * 16 ints
    float*  racc1  = (float*)(w + (16u << 10));             // 16 KB
    float*  racc2  = (float*)(w + (32u << 10));             // contiguous with racc1
    float*  ab1    = (float*)(w + (48u << 10));
    float*  ab2    = (float*)(w + (52u << 10));
    unsigned short* pw1 = (unsigned short*)(w + (64u << 10));   // 16 KB
    unsigned short* pw2 = (unsigned short*)(w + (80u << 10));   // 32 KB
    float*  pb     = (float*)(w + (128u << 10));            // 64 KB
    // arrays
    float*  rs_s   = (float*)(w + (1024u << 10));           // 512 KB
    float*  rsd    = (float*)(w + (1536u << 10));           // 512 KB
    int*    degd   = (int*)(w + (2048u << 10));             // 512 KB
    int*    offs   = (int*)(w + (2560u << 10));             // 512 KB
    float*  part   = (float*)(w + (3u << 20));              // 2 MB: 3..5
    int*    shist  = (int*)(w + (5u << 20));                // 4 MB: 5..9
    int*    dhist  = (int*)(w + (9u << 20));                // 4 MB: 9..13
    unsigned* csr2 = (unsigned*)(w + (13u << 20));          // 10 MB: 13..23
    unsigned* mbuf = (unsigned*)(w + (23u << 20));          // 32 MB: 23..55 (h2pre)
    unsigned* hbuf = (unsigned*)(w + (55u << 20));          // 32 MB: 55..87 (h1pre)
    uint2*    recs = (uint2*)(w + (87u << 20));             // 20 MB: 87..107
    unsigned* f8x  = (unsigned*)(w + (107u << 20));         // 8 MB: 107..115 (features fp8)
    unsigned* f8buf= (unsigned*)(w + (123u << 20));         // 16 MB: 123..139 (h1 fp8)

    // prep (feature->fp8 + init + packw + csr2 zero, fused)
    k_prep<<<10765, 256, 0, stream>>>(features, f8x, W1, pw1, W2, pw2, gcur, racc1, csr2);

    // CSR build
    k_part<<<EE / 4096, 256, 0, stream>>>(src, dst, ew, gcur, recs);
    k_hist<<<BG * 8, 1024, 0, stream>>>(recs, gcur, shist, dhist);
    k_offs<<<BG, 1024, 0, stream>>>(shist, dhist, rs_s, rsd, degd, offs);
    k_place<<<BG * 8, 1024, 0, stream>>>(recs, gcur, dhist, rs_s, csr2);

    // ---- layer 1 (fused agg+gemm; gathers fp8 features) ----
    k_aggemm1<<<NN / 64, 256, 0, stream>>>(f8x, csr2, offs, degd, rsd,
                                           (const short*)pw1, (unsigned short*)hbuf, part);
    k_red<<<64, 256, 0, stream>>>(part, pb);
    k_coef<<<1, 256, 0, stream>>>(pb, gamma1, beta1, alpha1, ab1);
    k_normro<true><<<NN / 64, 256, 0, stream>>>(hbuf, ab1, racc1, (unsigned short*)f8buf);

    // ---- layer 2 (fused agg+gemm; gathers fp8 h1, writes mbuf) ----
    k_aggemm2<<<NN / 64, 256, 0, stream>>>(f8buf, csr2, offs, degd, rsd,
                                           (const short*)pw2, (unsigned short*)mbuf, part);
    k_red<<<64, 256, 0, stream>>>(part, pb);
    k_coef<<<1, 256, 0, stream>>>(pb, gamma2, beta2, alpha2, ab2);
    k_normro<false><<<NN / 64, 256, 0, stream>>>(mbuf, ab2, racc2, nullptr);

    // ---- head ----
    k_final<<<1, 512, 0, stream>>>(racc1, racc2, Wc, out);
}